// Round 5
// baseline (910.586 us; speedup 1.0000x reference)
//
#include <hip/hip_runtime.h>
#include <math.h>
#include <stdint.h>

#define E_EDGES 131072
#define NN 32768      // NUM_NODES
#define DMEM 256
#define DEDGE 128
#define TDIM 64
#define HID 512
#define MSGD 256
#define INDIM 704     // 2*256+128+64

typedef __bf16 bf16_t;
typedef bf16_t bf16x8 __attribute__((ext_vector_type(8)));
typedef float f32x4 __attribute__((ext_vector_type(4)));

__device__ __forceinline__ unsigned short f2bf(float f) {
  unsigned int u = __float_as_uint(f);
  u += 0x7FFF + ((u >> 16) & 1);   // round-to-nearest-even
  return (unsigned short)(u >> 16);
}

__device__ __forceinline__ void gl_lds16(const bf16_t* g, bf16_t* l) {
  __builtin_amdgcn_global_load_lds(
      (__attribute__((address_space(1))) void*)(g),
      (__attribute__((address_space(3))) void*)(l), 16, 0, 0);
}

__global__ void cvt_bf16(const float* __restrict__ in, unsigned short* __restrict__ out, int n) {
  int i = blockIdx.x * 256 + threadIdx.x;
  if (i < n) out[i] = f2bf(in[i]);
}

// Granule swizzle for [R][32]-bf16 LDS tiles (row = 4 granules of 16B):
//   physical granule p of row r holds logical granule p ^ ((r>>1)&3).
//   Staging writes LINEAR (thread t -> row t>>2, granule t&3), source column
//   pre-swizzled: gs8 = ((t&3)^((t>>3)&3))*8.  Frag reads use
//   kqs = ((lane>>4)^((lane>>1)&3))*8.  -> 16-lane group spans all banks.

// ---------------- fused GEMM1+GEMM2 over dst-sorted edges, pipelined ----------------
__global__ __launch_bounds__(512) void gemm12_fused(
    const float* __restrict__ src, const float* __restrict__ dmem,
    const float* __restrict__ edge, const float* __restrict__ rel,
    const float* __restrict__ tw, const float* __restrict__ tb,
    const bf16_t* __restrict__ w1b, const float* __restrict__ b1,
    const bf16_t* __restrict__ w2b, const float* __restrict__ b2,
    const int* __restrict__ perm, const int* __restrict__ dsts,
    float* __restrict__ sums) {
  // 149,504 B union (74752 bf16):
  //   phase 1 (dbuf): A0@0(4096) A1@4096 B0@8192(16384) B1@24576
  //   phase 1.5/2:    hL [128][520] @0, sB2 [256][32] @66560
  //   epilogue:       msgL f32 [128][260] @0
  __shared__ alignas(16) bf16_t smem[74752];
  __shared__ float sTW[64], sTB[64], sRel[128];
  __shared__ int sPerm[128], sDst[128];
  bf16_t* hL  = smem;                 // [128][520]
  bf16_t* sB2 = smem + 66560;         // [256][32]

  const int bm = blockIdx.x;          // 1024 blocks
  const int t = threadIdx.x;
  const int lane = t & 63;
  const int wave = t >> 6;
  const int wm  = (wave >> 2) * 64;   // 0 / 64
  const int wn1 = (wave & 3) * 128;   // phase-1 wave col (tile 64x128)
  const int wn2 = (wave & 3) * 64;    // phase-2 wave col (tile 64x64)

  if (t < 64) { sTW[t] = tw[t]; sTB[t] = tb[t]; }
  if (t < 128) {
    int e = perm[bm * 128 + t];
    sPerm[t] = e;
    sRel[t] = rel[e];
    sDst[t] = dsts[bm * 128 + t];
  }
  __syncthreads();

  f32x4 acc[4][8];
#pragma unroll
  for (int i = 0; i < 4; i++)
#pragma unroll
    for (int j = 0; j < 8; j++) acc[i][j] = (f32x4){0.f, 0.f, 0.f, 0.f};

  const int ar   = t >> 2;                          // staging row 0..127
  const int lin8 = (t & 3) * 8;                     // linear granule offset
  const int gs8  = (((t & 3) ^ ((t >> 3) & 3))) * 8; // swizzled source granule
  const size_t arow = (size_t)sPerm[ar];
  const float rv0 = sRel[ar];
  const bf16_t* gB = w1b + (size_t)ar * 704 + gs8;

  const int lrow = lane & 15;
  const int kqs  = ((lane >> 4) ^ ((lane >> 1) & 3)) * 8;  // swizzled frag granule
  const int kql  = (lane >> 4) * 8;                        // linear (for hL)

  f32x4 uP, vP;  // A prefetch regs, hold chunk c+1 at loop entry of iter c

  // ---- phase-1 prologue: stage chunk 0 into buf0, prefetch chunk 1 A ----
  {
    f32x4 u0 = *(const f32x4*)(src + arow * 256 + gs8);
    f32x4 v0 = *(const f32x4*)(src + arow * 256 + gs8 + 4);
    bf16_t* lB = smem + 8192 + (size_t)t * 8;
    gl_lds16(gB,                     lB);
    gl_lds16(gB + (size_t)128 * 704, lB + 4096);
    gl_lds16(gB + (size_t)256 * 704, lB + 8192);
    gl_lds16(gB + (size_t)384 * 704, lB + 12288);
    gB += 32;
    // prefetch A chunk 1 (col 32, src region)
    uP = *(const f32x4*)(src + arow * 256 + 32 + gs8);
    vP = *(const f32x4*)(src + arow * 256 + 32 + gs8 + 4);
    bf16x8 av;
    av[0] = (bf16_t)u0[0]; av[1] = (bf16_t)u0[1]; av[2] = (bf16_t)u0[2]; av[3] = (bf16_t)u0[3];
    av[4] = (bf16_t)v0[0]; av[5] = (bf16_t)v0[1]; av[6] = (bf16_t)v0[2]; av[7] = (bf16_t)v0[3];
    *(bf16x8*)(smem + ar * 32 + lin8) = av;
  }
  __syncthreads();

  int cur = 0;
  for (int c = 0; c < 22; ++c) {
    const int cn = c + 1;
    const bool more = (cn < 22);
    f32x4 uN, vN;
    if (c + 2 < 20) {                  // issue A-load 2 steps ahead (HBM latency)
      const int col = (c + 2) * 32;
      const float* p;
      if (col < 256)      p = src  + arow * 256 + col + gs8;
      else if (col < 512) p = dmem + arow * 256 + (col - 256) + gs8;
      else                p = edge + arow * 128 + (col - 512) + gs8;
      uN = *(const f32x4*)p;
      vN = *(const f32x4*)(p + 4);
    }
    const int nxt = cur ^ 1;
    if (more) {                        // issue next w1 tile into other buffer
      bf16_t* lB = smem + (nxt ? 24576 : 8192) + (size_t)t * 8;
      gl_lds16(gB,                     lB);
      gl_lds16(gB + (size_t)128 * 704, lB + 4096);
      gl_lds16(gB + (size_t)256 * 704, lB + 8192);
      gl_lds16(gB + (size_t)384 * 704, lB + 12288);
      gB += 32;
    }

    const bf16_t* bA = smem + (cur ? 4096 : 0);
    const bf16_t* bB = smem + (cur ? 24576 : 8192);
    bf16x8 af[4], bfr[8];
#pragma unroll
    for (int i = 0; i < 4; i++) af[i]  = *(const bf16x8*)(bA + (wm  + i * 16 + lrow) * 32 + kqs);
#pragma unroll
    for (int i = 0; i < 8; i++) bfr[i] = *(const bf16x8*)(bB + (wn1 + i * 16 + lrow) * 32 + kqs);

    __builtin_amdgcn_s_setprio(1);
#pragma unroll
    for (int mi = 0; mi < 4; mi++)
#pragma unroll
      for (int ni = 0; ni < 8; ni++)
        acc[mi][ni] = __builtin_amdgcn_mfma_f32_16x16x32_bf16(af[mi], bfr[ni], acc[mi][ni], 0, 0, 0);
    __builtin_amdgcn_s_setprio(0);

    if (more) {
      bf16x8 av;
      if (cn < 20) {
        av[0] = (bf16_t)uP[0]; av[1] = (bf16_t)uP[1]; av[2] = (bf16_t)uP[2]; av[3] = (bf16_t)uP[3];
        av[4] = (bf16_t)vP[0]; av[5] = (bf16_t)vP[1]; av[6] = (bf16_t)vP[2]; av[7] = (bf16_t)vP[3];
      } else {
        int kk = cn * 32 - 640 + gs8;
#pragma unroll
        for (int j = 0; j < 8; j++)
          av[j] = (bf16_t)cosf(rv0 * sTW[kk + j] + sTB[kk + j]);
      }
      *(bf16x8*)(smem + (nxt ? 4096 : 0) + ar * 32 + lin8) = av;
      uP = uN; vP = vN;
    }
    __syncthreads();
    cur = nxt;
  }

  // ---- phase 1.5: relu+bias, h -> LDS (bf16, padded stride 520, linear) ----
  const int crow = (lane >> 4) * 4;
  const int ccol = lane & 15;
#pragma unroll
  for (int ni = 0; ni < 8; ni++) {
    int col = wn1 + ni * 16 + ccol;
    float bv = b1[col];
#pragma unroll
    for (int mi = 0; mi < 4; mi++) {
#pragma unroll
      for (int r = 0; r < 4; r++) {
        float v = fmaxf(acc[mi][ni][r] + bv, 0.f);
        ((unsigned short*)hL)[(wm + mi * 16 + crow + r) * 520 + col] = f2bf(v);
      }
    }
  }

  // ---- phase 2: msg = h @ w2^T + b2 ----
  f32x4 acc2[4][4];
#pragma unroll
  for (int i = 0; i < 4; i++)
#pragma unroll
    for (int j = 0; j < 4; j++) acc2[i][j] = (f32x4){0.f, 0.f, 0.f, 0.f};

  const bf16_t* gW2 = w2b + (size_t)ar * 512 + gs8;
  bf16_t* lB2 = sB2 + (size_t)t * 8;

  gl_lds16(gW2,                     lB2);
  gl_lds16(gW2 + (size_t)128 * 512, lB2 + 4096);
  gW2 += 32;
  __syncthreads();   // drains hL ds_writes + sB2 gl_lds

  for (int k0 = 0; k0 < HID; k0 += 32) {
    bf16x8 af2[4], bf2[4];
#pragma unroll
    for (int i = 0; i < 4; i++)
      af2[i] = *(const bf16x8*)(hL + (wm + i * 16 + lrow) * 520 + k0 + kql);
#pragma unroll
    for (int i = 0; i < 4; i++)
      bf2[i] = *(const bf16x8*)(sB2 + (wn2 + i * 16 + lrow) * 32 + kqs);
    __syncthreads();   // reads done -> safe to overwrite sB2

    if (k0 + 32 < HID) {
      gl_lds16(gW2,                     lB2);
      gl_lds16(gW2 + (size_t)128 * 512, lB2 + 4096);
      gW2 += 32;
    }

    __builtin_amdgcn_s_setprio(1);
#pragma unroll
    for (int mi = 0; mi < 4; mi++)
#pragma unroll
      for (int ni = 0; ni < 4; ni++)
        acc2[mi][ni] = __builtin_amdgcn_mfma_f32_16x16x32_bf16(af2[mi], bf2[ni], acc2[mi][ni], 0, 0, 0);
    __builtin_amdgcn_s_setprio(0);
    __syncthreads();
  }

  // ---- epilogue: msg -> LDS f32, segment-reduce sorted runs ----
  {
    float* msgL = (float*)smem;      // [128][260] padded
#pragma unroll
    for (int ni = 0; ni < 4; ni++) {
      int gcol = wn2 + ni * 16 + ccol;
      float bv = b2[gcol];
#pragma unroll
      for (int mi = 0; mi < 4; mi++) {
#pragma unroll
        for (int r = 0; r < 4; r++)
          msgL[(wm + mi * 16 + crow + r) * 260 + gcol] = acc2[mi][ni][r] + bv;
      }
    }
    __syncthreads();

    const int c = t & 255;           // column
    const int h = t >> 8;            // row half 0/1 (wave-uniform)
    int r = h * 64;
    const int rend = h * 64 + 64;
    while (r < rend) {
      int id = sDst[r];
      if (r > 0 && sDst[r - 1] == id) { r++; continue; }  // mid-run: owned by earlier head
      float s2 = msgL[r * 260 + c];
      int rr = r + 1;
      while (rr < 128 && sDst[rr] == id) { s2 += msgL[rr * 260 + c]; rr++; }
      if (r == 0 || rr == 128)       // run may continue in neighbor block
        atomicAdd(&sums[(size_t)id * 256 + c], s2);
      else                           // node fully owned by this block
        sums[(size_t)id * 256 + c] = s2;
      r = rr;
    }
  }
}

// ---------------- fused GRU: agg build + S=[agg|prev]@[wih|whh]^T + ghn + gate ----------------
// 512 blocks x 64 node-slots. S (N=768, K=512) gives gi+gh for r,z gates;
// ghn (N=256) reuses the staged whh rows 512..767 during K-steps 8..15.
// n = tanh(S_n + (r-1)*ghn).  Gate + store done in LDS per 16-row group.
__global__ __launch_bounds__(512, 2) void gru_fused(
    const float* __restrict__ sums, const int* __restrict__ icnt,
    const int* __restrict__ slot_id, const float* __restrict__ dmem,
    const bf16_t* __restrict__ wihb, const bf16_t* __restrict__ whhb,
    const float* __restrict__ bih, const float* __restrict__ bhh,
    float* __restrict__ outm) {
  // sm: B tile [768][32] @0 (24576 elems), A tile [64][32] @24576 (2048 elems)
  // epilogue union: S16 [16][776] @0 (12416), G16 [16][264] @12416 (4224)
  __shared__ alignas(16) bf16_t sm[26624];
  __shared__ float sBS[768], sBG[256], sInv[64];
  __shared__ int sId[64];

  const int bm = blockIdx.x;
  const int t = threadIdx.x;
  const int lane = t & 63;
  const int wave = t >> 6;
  const int ws = wave * 96;          // S col slice
  const int lrow = lane & 15;
  const int gs8 = (((t & 3) ^ ((t >> 3) & 3))) * 8;
  const int kqs = ((lane >> 4) ^ ((lane >> 1) & 3)) * 8;
  const int arw = t >> 2;            // staging row (t<256)

  if (t < 64) {
    int id = slot_id[bm * 64 + t];
    sId[t] = id;
    sInv[t] = (id >= 0) ? (1.f / fmaxf((float)icnt[id], 1.f)) : 0.f;
  }
  for (int i = t; i < 768; i += 512) sBS[i] = bih[i] + bhh[i];
  if (t < 256) sBG[t] = bhh[512 + t];
  __syncthreads();

  f32x4 accS[4][6];
#pragma unroll
  for (int i = 0; i < 4; i++)
#pragma unroll
    for (int j = 0; j < 6; j++) accS[i][j] = (f32x4){0.f, 0.f, 0.f, 0.f};
  f32x4 accG[4][2];
#pragma unroll
  for (int i = 0; i < 4; i++)
#pragma unroll
    for (int j = 0; j < 2; j++) accG[i][j] = (f32x4){0.f, 0.f, 0.f, 0.f};

  bf16_t* sA = sm + 24576;

  // ---- prologue: stage step 0 (A from sums, B = wih cols 0..31) ----
  if (t < 256) {
    f32x4 u = (f32x4){0.f, 0.f, 0.f, 0.f}, v = u;
    int id = sId[arw];
    if (id >= 0) {
      const float* p = sums + (size_t)id * 256 + gs8;
      u = *(const f32x4*)p; v = *(const f32x4*)(p + 4);
    }
    float inv = sInv[arw];
    bf16x8 av;
#pragma unroll
    for (int j = 0; j < 4; j++) { av[j] = (bf16_t)(u[j] * inv); av[4 + j] = (bf16_t)(v[j] * inv); }
    *(bf16x8*)(sA + t * 8) = av;
  }
#pragma unroll
  for (int ch = 0; ch < 6; ++ch)
    gl_lds16(wihb + ((size_t)(ch * 128) + arw) * 256 + gs8, sm + ch * 4096 + (size_t)t * 8);
  __syncthreads();

  for (int k = 0; k < 16; ++k) {
    const bool gph = (k >= 8);
    bf16x8 af[4], bfS[6], bg[2];
#pragma unroll
    for (int i = 0; i < 4; i++)
      af[i] = *(const bf16x8*)(sA + (i * 16 + lrow) * 32 + kqs);
#pragma unroll
    for (int n = 0; n < 6; n++)
      bfS[n] = *(const bf16x8*)(sm + (ws + n * 16 + lrow) * 32 + kqs);
    if (gph) {
#pragma unroll
      for (int g = 0; g < 2; g++)
        bg[g] = *(const bf16x8*)(sm + (512 + wave * 32 + g * 16 + lrow) * 32 + kqs);
    }
    __syncthreads();   // reads done -> tiles reusable

    const int kn = k + 1;
    f32x4 u = (f32x4){0.f, 0.f, 0.f, 0.f}, v = u;
    if (kn < 16) {
      const int k0n = kn * 32;
      if (t < 256) {
        if (k0n < 256) {
          int id = sId[arw];
          if (id >= 0) {
            const float* p = sums + (size_t)id * 256 + k0n + gs8;
            u = *(const f32x4*)p; v = *(const f32x4*)(p + 4);
          }
        } else {
          const float* p = dmem + ((size_t)(bm * 64 + arw)) * 256 + (k0n - 256) + gs8;
          u = *(const f32x4*)p; v = *(const f32x4*)(p + 4);
        }
      }
      const bf16_t* Bs = (k0n < 256) ? wihb : whhb;
      const int kk0 = k0n & 255;
#pragma unroll
      for (int ch = 0; ch < 6; ++ch)
        gl_lds16(Bs + ((size_t)(ch * 128) + arw) * 256 + kk0 + gs8, sm + ch * 4096 + (size_t)t * 8);
    }

    __builtin_amdgcn_s_setprio(1);
#pragma unroll
    for (int i = 0; i < 4; i++)
#pragma unroll
      for (int n = 0; n < 6; n++)
        accS[i][n] = __builtin_amdgcn_mfma_f32_16x16x32_bf16(af[i], bfS[n], accS[i][n], 0, 0, 0);
    if (gph) {
#pragma unroll
      for (int i = 0; i < 4; i++)
#pragma unroll
        for (int g = 0; g < 2; g++)
          accG[i][g] = __builtin_amdgcn_mfma_f32_16x16x32_bf16(af[i], bg[g], accG[i][g], 0, 0, 0);
    }
    __builtin_amdgcn_s_setprio(0);

    if (kn < 16 && t < 256) {
      bf16x8 av;
      if (kn * 32 < 256) {
        float inv = sInv[arw];
#pragma unroll
        for (int j = 0; j < 4; j++) { av[j] = (bf16_t)(u[j] * inv); av[4 + j] = (bf16_t)(v[j] * inv); }
      } else {
#pragma unroll
        for (int j = 0; j < 4; j++) { av[j] = (bf16_t)u[j]; av[4 + j] = (bf16_t)v[j]; }
      }
      *(bf16x8*)(sA + t * 8) = av;
    }
    __syncthreads();   // stage drained (after MFMA)
  }

  // ---- epilogue: per 16-row group, gate in LDS ----
  bf16_t* sS = sm;            // [16][776]
  bf16_t* sG = sm + 12416;    // [16][264]
  const int crow = (lane >> 4) * 4;
  const int ccol = lane & 15;
  const int col = t & 255;
  const int rh = t >> 8;
  for (int mi = 0; mi < 4; ++mi) {
#pragma unroll
    for (int n = 0; n < 6; n++) {
      int c = ws + n * 16 + ccol;
      float b = sBS[c];
#pragma unroll
      for (int r = 0; r < 4; r++)
        sS[(crow + r) * 776 + c] = (bf16_t)(accS[mi][n][r] + b);
    }
#pragma unroll
    for (int g = 0; g < 2; g++) {
      int c = wave * 32 + g * 16 + ccol;
      float b = sBG[c];
#pragma unroll
      for (int r = 0; r < 4; r++)
        sG[(crow + r) * 264 + c] = (bf16_t)(accG[mi][g][r] + b);
    }
    __syncthreads();
#pragma unroll
    for (int p = 0; p < 8; ++p) {
      int r16 = rh * 8 + p;
      size_t j = (size_t)bm * 64 + mi * 16 + r16;
      float Sr = (float)sS[r16 * 776 + col];
      float Sz = (float)sS[r16 * 776 + 256 + col];
      float Sn = (float)sS[r16 * 776 + 512 + col];
      float gn = (float)sG[r16 * 264 + col];
      float rg = 1.f / (1.f + expf(-Sr));
      float zg = 1.f / (1.f + expf(-Sz));
      float ng = tanhf(Sn + (rg - 1.f) * gn);
      float prev = dmem[j * 256 + col];
      outm[j * 256 + col] = (1.f - zg) * ng + zg * prev;
    }
    __syncthreads();
  }
}

// ---------------- unique / sort machinery ----------------
__global__ void mark_k(const int* __restrict__ dst, int* __restrict__ icnt) {
  int e = blockIdx.x * 256 + threadIdx.x;
  if (e < E_EDGES) atomicAdd(&icnt[dst[e]], 1);
}

__global__ void fill_k(float* __restrict__ uo, int* __restrict__ slot_id) {
  int j = blockIdx.x * 256 + threadIdx.x;
  if (j < NN) { uo[j] = (float)NN; slot_id[j] = -1; }
}

// dual scan over icnt: rank = exclusive scan of (icnt>0), offs = exclusive scan of icnt
__global__ void scan2_k(const int* __restrict__ icnt, int* __restrict__ rank,
                        int* __restrict__ offs) {
  __shared__ int pf[1024], pc[1024];
  int t = threadIdx.x;
  int base = t * 32;
  int sf = 0, sc = 0;
  for (int i = 0; i < 32; i++) { int v = icnt[base + i]; sf += (v > 0); sc += v; }
  pf[t] = sf; pc[t] = sc;
  __syncthreads();
  for (int off = 1; off < 1024; off <<= 1) {
    int vf = (t >= off) ? pf[t - off] : 0;
    int vc = (t >= off) ? pc[t - off] : 0;
    __syncthreads();
    pf[t] += vf; pc[t] += vc;
    __syncthreads();
  }
  int runf = (t == 0) ? 0 : pf[t - 1];
  int runc = (t == 0) ? 0 : pc[t - 1];
  for (int i = 0; i < 32; i++) {
    int v = icnt[base + i];
    rank[base + i] = runf; runf += (v > 0);
    offs[base + i] = runc; runc += v;
  }
}

__global__ void scatter_ids(const int* __restrict__ icnt, const int* __restrict__ rank,
                            float* __restrict__ uo, int* __restrict__ slot_id) {
  int id = blockIdx.x * 256 + threadIdx.x;
  if (id < NN && icnt[id] > 0) {
    int s = rank[id];
    uo[s] = (float)id;
    slot_id[s] = id;
  }
}

// counting-sort: perm[pos] = edge index, dsts[pos] = its dst id (sorted)
__global__ void scatter_edges(const int* __restrict__ dst, const int* __restrict__ offs,
                              int* __restrict__ cursor, int* __restrict__ perm,
                              int* __restrict__ dsts) {
  int e = blockIdx.x * 256 + threadIdx.x;
  if (e < E_EDGES) {
    int id = dst[e];
    int pos = offs[id] + atomicAdd(&cursor[id], 1);
    perm[pos] = e;
    dsts[pos] = id;
  }
}

extern "C" void kernel_launch(void* const* d_in, const int* in_sizes, int n_in,
                              void* d_out, int out_size, void* d_ws, size_t ws_size,
                              hipStream_t stream) {
  const float* rel  = (const float*)d_in[0];
  const float* src  = (const float*)d_in[1];
  const float* dmem = (const float*)d_in[2];
  const float* edge = (const float*)d_in[3];
  const int*   dst  = (const int*)d_in[4];
  const float* tw   = (const float*)d_in[5];
  const float* tb   = (const float*)d_in[6];
  const float* w1   = (const float*)d_in[7];
  const float* b1   = (const float*)d_in[8];
  const float* w2   = (const float*)d_in[9];
  const float* b2   = (const float*)d_in[10];
  const float* wih  = (const float*)d_in[11];
  const float* whh  = (const float*)d_in[12];
  const float* bih  = (const float*)d_in[13];
  const float* bhh  = (const float*)d_in[14];

  char* ws = (char*)d_ws;
  size_t o = 0;
  auto take = [&](size_t bytes) -> char* {
    char* p = ws + o;
    o += (bytes + 255) & ~(size_t)255;
    return p;
  };

  float* sums           = (float*)take((size_t)NN * 256 * 4);
  int*   icnt           = (int*)take((size_t)NN * 4);
  int*   rank           = (int*)take((size_t)NN * 4);
  int*   offs           = (int*)take((size_t)NN * 4);
  int*   cursor         = (int*)take((size_t)NN * 4);
  int*   slot_id        = (int*)take((size_t)NN * 4);
  int*   perm           = (int*)take((size_t)E_EDGES * 4);
  int*   dsts           = (int*)take((size_t)E_EDGES * 4);
  unsigned short* w1b   = (unsigned short*)take((size_t)HID * INDIM * 2);
  unsigned short* w2b   = (unsigned short*)take((size_t)MSGD * HID * 2);
  unsigned short* wihb  = (unsigned short*)take((size_t)768 * 256 * 2);
  unsigned short* whhb  = (unsigned short*)take((size_t)768 * 256 * 2);

  float* outf = (float*)d_out;

  hipMemsetAsync(sums, 0, (size_t)NN * 256 * 4, stream);
  hipMemsetAsync(icnt, 0, (size_t)NN * 4, stream);
  hipMemsetAsync(cursor, 0, (size_t)NN * 4, stream);

  int n1 = HID * INDIM;
  int n2 = MSGD * HID;
  int n3 = 768 * 256;
  cvt_bf16<<<(n1 + 255) / 256, 256, 0, stream>>>(w1, w1b, n1);
  cvt_bf16<<<(n2 + 255) / 256, 256, 0, stream>>>(w2, w2b, n2);
  cvt_bf16<<<(n3 + 255) / 256, 256, 0, stream>>>(wih, wihb, n3);
  cvt_bf16<<<(n3 + 255) / 256, 256, 0, stream>>>(whh, whhb, n3);

  mark_k<<<E_EDGES / 256, 256, 0, stream>>>(dst, icnt);
  scan2_k<<<1, 1024, 0, stream>>>(icnt, rank, offs);
  scatter_edges<<<E_EDGES / 256, 256, 0, stream>>>(dst, offs, cursor, perm, dsts);

  fill_k<<<NN / 256, 256, 0, stream>>>(outf, slot_id);
  scatter_ids<<<NN / 256, 256, 0, stream>>>(icnt, rank, outf, slot_id);

  // fused: h = relu(X@w1^T+b1) in LDS; msg = h@w2^T+b2 segment-reduced into sums
  gemm12_fused<<<dim3(E_EDGES / 128), 512, 0, stream>>>(
      src, dmem, edge, rel, tw, tb, (const bf16_t*)w1b, b1,
      (const bf16_t*)w2b, b2, perm, dsts, sums);

  // fused GRU tail: agg build + combined GEMM + gate -> memories
  gru_fused<<<dim3(NN / 64), 512, 0, stream>>>(
      sums, icnt, slot_id, dmem,
      (const bf16_t*)wihb, (const bf16_t*)whhb, bih, bhh, outf + NN);
}